// Round 5
// baseline (116.602 us; speedup 1.0000x reference)
//
#include <hip/hip_runtime.h>
#include <cfloat>
#include <cmath>

#define B_    32
#define C_    2048
#define NTILES (B_ * C_)
#define NREG  14

typedef float f4 __attribute__((ext_vector_type(4)));   // native vector: OK for nontemporal builtin

// region r -> row range [c_rs, c_re), column-range index c_ci
// col-range order: 0=A[0,21) 1=B[11,32) 2=C[0,16) 3=D[8,24) 4=E[16,32) 5=F[0,32)
__constant__ int c_rs[NREG] = {0, 0, 0,11,11, 0, 0, 0, 8, 8, 8,16,16,16};
__constant__ int c_re[NREG] = {32,21,21,32,32,16,16,16,24,24,24,32,32,32};
__constant__ int c_ci[NREG] = {5, 0, 1, 0, 1, 2, 3, 4, 2, 3, 4, 2, 3, 4};

// Phase 1: 8 tiles (= 8 channels of one batch) per block.
// x is read exactly once -> nontemporal loads (streaming, no cache alloc).
__global__ __launch_bounds__(256) void rmac_phase1(const float* __restrict__ x,
                                                   float* __restrict__ m,
                                                   float* __restrict__ partials) {
    __shared__ float lds[4][64][6];
    __shared__ float sq[4][2][NREG];
    const int tid  = threadIdx.x;
    const int wv   = tid >> 6;      // wave 0..3
    const int l    = tid & 63;      // lane
    const int half = l >> 5;        // which of the wave's 2 tiles
    const int row  = l & 31;        // row within tile
    const long tile = (long)blockIdx.x * 8 + wv * 2 + half;
    const f4* p = (const f4*)(x + tile * 1024 + row * 32);

    f4 v0 = __builtin_nontemporal_load(p + 0);
    f4 v1 = __builtin_nontemporal_load(p + 1);
    f4 v2 = __builtin_nontemporal_load(p + 2);
    f4 v3 = __builtin_nontemporal_load(p + 3);
    f4 v4 = __builtin_nontemporal_load(p + 4);
    f4 v5 = __builtin_nontemporal_load(p + 5);
    f4 v6 = __builtin_nontemporal_load(p + 6);
    f4 v7 = __builtin_nontemporal_load(p + 7);

    // disjoint column segments: [0,8) [8,11) [11,16) [16,21) [21,24) [24,32)
    float s0 = fmaxf(fmaxf(fmaxf(v0[0],v0[1]),fmaxf(v0[2],v0[3])),
                     fmaxf(fmaxf(v1[0],v1[1]),fmaxf(v1[2],v1[3])));         // 0-7
    float s1 = fmaxf(v2[0], fmaxf(v2[1], v2[2]));                           // 8-10
    float s2 = fmaxf(fmaxf(v2[3], v3[0]), fmaxf(fmaxf(v3[1],v3[2]), v3[3]));// 11-15
    float s3 = fmaxf(fmaxf(v4[0], v4[1]), fmaxf(fmaxf(v4[2],v4[3]), v5[0]));// 16-20
    float s4 = fmaxf(v5[1], fmaxf(v5[2], v5[3]));                           // 21-23
    float s5 = fmaxf(fmaxf(fmaxf(v6[0],v6[1]),fmaxf(v6[2],v6[3])),
                     fmaxf(fmaxf(v7[0],v7[1]),fmaxf(v7[2],v7[3])));         // 24-31

    float A  = fmaxf(fmaxf(s0,s1), fmaxf(s2,s3));   // cols [0,21)
    float Bv = fmaxf(fmaxf(s2,s3), fmaxf(s4,s5));   // cols [11,32)
    float Cv = fmaxf(fmaxf(s0,s1), s2);             // cols [0,16)
    float Dv = fmaxf(fmaxf(s1,s2), fmaxf(s3,s4));   // cols [8,24)
    float E  = fmaxf(s3, fmaxf(s4,s5));             // cols [16,32)
    float F  = fmaxf(A, fmaxf(s4,s5));              // cols [0,32)

    lds[wv][l][0]=A;  lds[wv][l][1]=Bv; lds[wv][l][2]=Cv;
    lds[wv][l][3]=Dv; lds[wv][l][4]=E;  lds[wv][l][5]=F;
    __syncthreads();

    const int reg = (l < NREG) ? l : ((l >= 32 && l < 32 + NREG) ? (l - 32) : -1);
    if (reg >= 0) {
        const int h = l >> 5;
        const int a = c_rs[reg], b = c_re[reg], c = c_ci[reg];
        float acc = -FLT_MAX;
        #pragma unroll
        for (int i = 0; i < 32; ++i) {
            float v = lds[wv][h * 32 + i][c];
            acc = (i >= a && i < b) ? fmaxf(acc, v) : acc;
        }
        const long t2 = (long)blockIdx.x * 8 + wv * 2 + h;
        m[t2 * 16 + reg] = acc;
        sq[wv][h][reg] = acc * acc;
    }
    __syncthreads();
    if (tid < NREG) {
        float s = 0.f;
        #pragma unroll
        for (int w = 0; w < 4; ++w)
            #pragma unroll
            for (int h2 = 0; h2 < 2; ++h2) s += sq[w][h2][tid];
        partials[(long)blockIdx.x * 16 + tid] = s;
    }
}

// Phase 2: 256 blocks (8 per batch). m-loads issued at entry (overlap the
// partials reduce). Partials reduce is transposed: thread t owns component
// t&15, sums 16 rows with coalesced loads, then 2 shfl_xor + tiny LDS.
__global__ __launch_bounds__(256) void rmac_phase2(const float* __restrict__ m,
                                                   const float* __restrict__ partials,
                                                   float* __restrict__ out) {
    const int t = threadIdx.x;
    const int b = blockIdx.x >> 3;                    // 8 blocks per batch

    // Issue the m loads for this thread's channel immediately (independent).
    const long g = (long)blockIdx.x * 256 + t;        // one channel per thread
    const float4* q = (const float4*)(m + g * 16);
    float4 a0 = q[0], a1 = q[1], a2 = q[2], a3 = q[3];

    // Transposed partial reduction: comp = t&15, rows (t>>4) + 16k, k=0..15.
    const int comp = t & 15;
    const int r0   = t >> 4;
    const float* pbase = partials + (long)b * 256 * 16;
    float acc = 0.f;
    #pragma unroll
    for (int k = 0; k < 16; ++k)
        acc += pbase[(r0 + k * 16) * 16 + comp];      // 256B/wave, coalesced
    acc += __shfl_xor(acc, 16, 64);
    acc += __shfl_xor(acc, 32, 64);

    __shared__ float sred[4][16];
    __shared__ float sinv[16];
    if ((t & 63) < 16) sred[t >> 6][comp] = acc;
    __syncthreads();
    if (t < NREG) {
        float s = sred[0][t] + sred[1][t] + sred[2][t] + sred[3][t];
        float w = (t == 0) ? 2.f : 1.f;   // full region appears twice in the sum
        sinv[t] = w / (sqrtf(s) + 1e-6f);
    }
    __syncthreads();

    float o = a0.x*sinv[0] + a0.y*sinv[1] + a0.z*sinv[2]  + a0.w*sinv[3]
            + a1.x*sinv[4] + a1.y*sinv[5] + a1.z*sinv[6]  + a1.w*sinv[7]
            + a2.x*sinv[8] + a2.y*sinv[9] + a2.z*sinv[10] + a2.w*sinv[11]
            + a3.x*sinv[12] + a3.y*sinv[13];
    out[g] = o;
}

extern "C" void kernel_launch(void* const* d_in, const int* in_sizes, int n_in,
                              void* d_out, int out_size, void* d_ws, size_t ws_size,
                              hipStream_t stream) {
    const float* x = (const float*)d_in[0];
    float* m        = (float*)d_ws;                   // 64K tiles * 16 f = 4 MiB
    float* partials = m + (long)NTILES * 16;          // 8192 blocks * 16 f = 512 KiB
    float* out      = (float*)d_out;
    rmac_phase1<<<NTILES / 8, 256, 0, stream>>>(x, m, partials);
    rmac_phase2<<<256, 256, 0, stream>>>(m, partials, out);
}

// Round 6
// 47.771 us; speedup vs baseline: 2.4409x; 2.4409x over previous
//
#include <hip/hip_runtime.h>
#include <cfloat>
#include <cmath>

#define B_    32
#define C_    2048
#define NTILES (B_ * C_)
#define NREG  14

// region r -> row range [c_rs, c_re), column-range index c_ci
// col-range order: 0=A[0,21) 1=B[11,32) 2=C[0,16) 3=D[8,24) 4=E[16,32) 5=F[0,32)
__constant__ int c_rs[NREG] = {0, 0, 0,11,11, 0, 0, 0, 8, 8, 8,16,16,16};
__constant__ int c_re[NREG] = {32,21,21,32,32,16,16,16,24,24,24,32,32,32};
__constant__ int c_ci[NREG] = {5, 0, 1, 0, 1, 2, 3, 4, 2, 3, 4, 2, 3, 4};

// Phase 1: 8 tiles (= 8 channels of one batch) per block.
// Plain cached float4 loads — nt-flagged loads measured 2.4x SLOWER (R5).
__global__ __launch_bounds__(256) void rmac_phase1(const float* __restrict__ x,
                                                   float* __restrict__ m,
                                                   float* __restrict__ partials) {
    __shared__ float lds[4][64][6];
    __shared__ float sq[4][2][NREG];
    const int tid  = threadIdx.x;
    const int wv   = tid >> 6;      // wave 0..3
    const int l    = tid & 63;      // lane
    const int half = l >> 5;        // which of the wave's 2 tiles
    const int row  = l & 31;        // row within tile
    const long tile = (long)blockIdx.x * 8 + wv * 2 + half;
    const float4* p = (const float4*)(x + tile * 1024 + row * 32);

    float4 v0 = p[0]; float4 v1 = p[1]; float4 v2 = p[2]; float4 v3 = p[3];
    float4 v4 = p[4]; float4 v5 = p[5]; float4 v6 = p[6]; float4 v7 = p[7];

    // disjoint column segments: [0,8) [8,11) [11,16) [16,21) [21,24) [24,32)
    float s0 = fmaxf(fmaxf(fmaxf(v0.x,v0.y),fmaxf(v0.z,v0.w)),
                     fmaxf(fmaxf(v1.x,v1.y),fmaxf(v1.z,v1.w)));           // 0-7
    float s1 = fmaxf(v2.x, fmaxf(v2.y, v2.z));                            // 8-10
    float s2 = fmaxf(fmaxf(v2.w, v3.x), fmaxf(fmaxf(v3.y,v3.z), v3.w));   // 11-15
    float s3 = fmaxf(fmaxf(v4.x, v4.y), fmaxf(fmaxf(v4.z,v4.w), v5.x));   // 16-20
    float s4 = fmaxf(v5.y, fmaxf(v5.z, v5.w));                            // 21-23
    float s5 = fmaxf(fmaxf(fmaxf(v6.x,v6.y),fmaxf(v6.z,v6.w)),
                     fmaxf(fmaxf(v7.x,v7.y),fmaxf(v7.z,v7.w)));           // 24-31

    float A  = fmaxf(fmaxf(s0,s1), fmaxf(s2,s3));   // cols [0,21)
    float Bv = fmaxf(fmaxf(s2,s3), fmaxf(s4,s5));   // cols [11,32)
    float Cv = fmaxf(fmaxf(s0,s1), s2);             // cols [0,16)
    float Dv = fmaxf(fmaxf(s1,s2), fmaxf(s3,s4));   // cols [8,24)
    float E  = fmaxf(s3, fmaxf(s4,s5));             // cols [16,32)
    float F  = fmaxf(A, fmaxf(s4,s5));              // cols [0,32)

    lds[wv][l][0]=A;  lds[wv][l][1]=Bv; lds[wv][l][2]=Cv;
    lds[wv][l][3]=Dv; lds[wv][l][4]=E;  lds[wv][l][5]=F;
    __syncthreads();

    const int reg = (l < NREG) ? l : ((l >= 32 && l < 32 + NREG) ? (l - 32) : -1);
    if (reg >= 0) {
        const int h = l >> 5;
        const int a = c_rs[reg], b = c_re[reg], c = c_ci[reg];
        float acc = -FLT_MAX;
        #pragma unroll
        for (int i = 0; i < 32; ++i) {
            float v = lds[wv][h * 32 + i][c];
            acc = (i >= a && i < b) ? fmaxf(acc, v) : acc;
        }
        const long t2 = (long)blockIdx.x * 8 + wv * 2 + h;
        m[t2 * 16 + reg] = acc;
        sq[wv][h][reg] = acc * acc;
    }
    __syncthreads();
    if (tid < NREG) {
        float s = 0.f;
        #pragma unroll
        for (int w = 0; w < 4; ++w)
            #pragma unroll
            for (int h2 = 0; h2 < 2; ++h2) s += sq[w][h2][tid];
        partials[(long)blockIdx.x * 16 + tid] = s;
    }
}

// Phase 2: 256 blocks (8 per batch). m-loads issued at entry (overlap the
// partials reduce). Partials reduce is transposed: thread t owns component
// t&15, sums 16 rows with coalesced loads, then 2 shfl_xor + tiny LDS.
__global__ __launch_bounds__(256) void rmac_phase2(const float* __restrict__ m,
                                                   const float* __restrict__ partials,
                                                   float* __restrict__ out) {
    const int t = threadIdx.x;
    const int b = blockIdx.x >> 3;                    // 8 blocks per batch

    // Issue the m loads for this thread's channel immediately (independent).
    const long g = (long)blockIdx.x * 256 + t;        // one channel per thread
    const float4* q = (const float4*)(m + g * 16);
    float4 a0 = q[0], a1 = q[1], a2 = q[2], a3 = q[3];

    // Transposed partial reduction: comp = t&15, rows (t>>4) + 16k, k=0..15.
    const int comp = t & 15;
    const int r0   = t >> 4;
    const float* pbase = partials + (long)b * 256 * 16;
    float acc = 0.f;
    #pragma unroll
    for (int k = 0; k < 16; ++k)
        acc += pbase[(r0 + k * 16) * 16 + comp];      // 256B/wave, coalesced
    acc += __shfl_xor(acc, 16, 64);
    acc += __shfl_xor(acc, 32, 64);

    __shared__ float sred[4][16];
    __shared__ float sinv[16];
    if ((t & 63) < 16) sred[t >> 6][comp] = acc;
    __syncthreads();
    if (t < NREG) {
        float s = sred[0][t] + sred[1][t] + sred[2][t] + sred[3][t];
        float w = (t == 0) ? 2.f : 1.f;   // full region appears twice in the sum
        sinv[t] = w / (sqrtf(s) + 1e-6f);
    }
    __syncthreads();

    float o = a0.x*sinv[0] + a0.y*sinv[1] + a0.z*sinv[2]  + a0.w*sinv[3]
            + a1.x*sinv[4] + a1.y*sinv[5] + a1.z*sinv[6]  + a1.w*sinv[7]
            + a2.x*sinv[8] + a2.y*sinv[9] + a2.z*sinv[10] + a2.w*sinv[11]
            + a3.x*sinv[12] + a3.y*sinv[13];
    out[g] = o;
}

extern "C" void kernel_launch(void* const* d_in, const int* in_sizes, int n_in,
                              void* d_out, int out_size, void* d_ws, size_t ws_size,
                              hipStream_t stream) {
    const float* x = (const float*)d_in[0];
    float* m        = (float*)d_ws;                   // 64K tiles * 16 f = 4 MiB
    float* partials = m + (long)NTILES * 16;          // 8192 blocks * 16 f = 512 KiB
    float* out      = (float*)d_out;
    rmac_phase1<<<NTILES / 8, 256, 0, stream>>>(x, m, partials);
    rmac_phase2<<<256, 256, 0, stream>>>(m, partials, out);
}